// Round 19
// baseline (194.890 us; speedup 1.0000x reference)
//
#include <hip/hip_runtime.h>

#define VB 0.22360679774997896f  // 20^-0.5

typedef __attribute__((ext_vector_type(8))) _Float16 half8;
typedef __attribute__((ext_vector_type(4))) float f32x4;

// workspace float offsets (R13/R16 layout)
#define Z1_OFF   0
#define Z2_OFF   655360
#define Z3_OFF   819200
#define GS1_OFF  860160
#define GQ1_OFF  860416
#define GS2_OFF  860672
#define GQ2_OFF  860736
#define GS3_OFF  860800
#define GQ3_OFF  860816
#define LV2_OFF  963232    // 64*400
#define LV3_OFF  988832    // 16*400
#define WH2_OFF  995232    // 6553600 halfs
#define WH3_OFF  4272032   // 1638400 halfs

#define WAVEBAR() __builtin_amdgcn_wave_barrier()

// LDS-only barrier (R18-verified): orders ds ops without draining vmcnt.
#define BARRIER_LGKM()                                        \
    asm volatile("s_waitcnt lgkmcnt(0)" ::: "memory");        \
    __builtin_amdgcn_sched_barrier(0);                        \
    __builtin_amdgcn_s_barrier();

// ---------------------------------------------------------------------------
// Fused stage 1: TWO blocks per patch (batch halves), 256 thr (4 waves),
// 71 KB LDS -> 2 blocks/CU (independent barrier groups overlap stalls).
// Twin blocks share an XCD so cores1 chunks L2-hit for the second reader.
// Math/scatter/barriers identical to R18-verified body. BN via atomics.
// ---------------------------------------------------------------------------
#define LOADW(W, ci)                                                          \
    {                                                                         \
        const float* wp_ = wbase + (size_t)(ci) * 7680;                       \
        _Pragma("unroll")                                                     \
        for (int k = 0; k < 8; ++k) {                                         \
            int i4 = tid + k * 256;                                           \
            if (i4 < 1920) W[k] = *(const float4*)(wp_ + i4 * 4);             \
        }                                                                     \
    }

#define SCATW(W, DST)                                                         \
    {                                                                         \
        _Pragma("unroll")                                                     \
        for (int k = 0; k < 8; ++k) {                                         \
            int i4 = tid + k * 256;                                           \
            if (i4 < 1920) {                                                  \
                float vals[4] = {W[k].x, W[k].y, W[k].z, W[k].w};             \
                _Pragma("unroll")                                             \
                for (int t = 0; t < 4; ++t)                                   \
                    DST[sAddr[k][t]] = (_Float16)vals[t];                     \
            }                                                                 \
        }                                                                     \
    }

#define CHUNKD(ci, W)                                                         \
    {                                                                         \
        f32x4 acc[5];                                                         \
        _Pragma("unroll")                                                     \
        for (int nt = 0; nt < 5; ++nt) acc[nt] = (f32x4){0.f, 0.f, 0.f, 0.f};\
        _Pragma("unroll")                                                     \
        for (int ks = 0; ks < 3; ++ks) {                                      \
            _Pragma("unroll")                                                 \
            for (int nt = 0; nt < 5; ++nt) {                                  \
                half8 bf = *(const half8*)&Fcur[((ks * 5 + nt) * 64 + l) * 8];\
                acc[nt] = __builtin_amdgcn_mfma_f32_16x16x32_f16(             \
                    af[ks], bf, acc[nt], 0, 0, 0);                            \
            }                                                                 \
        }                                                                     \
        _Pragma("unroll")                                                     \
        for (int nt = 0; nt < 5; ++nt) {                                      \
            _Pragma("unroll")                                                 \
            for (int r = 0; r < 4; ++r)                                       \
                Mw[(hi * 4 + r) * 84 + nt * 16 + row16] = acc[nt][r];         \
        }                                                                     \
        WAVEBAR();                                                            \
        _Pragma("unroll")                                                     \
        for (int ul = 0; ul < 4; ++ul) {                                      \
            float lvx = lw[bQ * 20 + ((ci) % 5) * 4 + ul];                    \
            _Pragma("unroll")                                                 \
            for (int j = 0; j < 5; ++j)                                       \
                lacc[j] += lvx * Mw[bQ * 84 + ul * 20 + mh * 5 + j];          \
        }                                                                     \
        WAVEBAR();                                                            \
        BARRIER_LGKM();                                                       \
        if ((ci) < 19) { SCATW(W, Fnxt) }                                     \
        BARRIER_LGKM();                                                       \
        { _Float16* t_ = Fcur; Fcur = Fnxt; Fnxt = t_; }                      \
        if ((ci) <= 16) { LOADW(W, (ci) + 3) }                                \
    }

#define SITE(nv, W0, W1, W2, W3, W4)                                          \
    {                                                                         \
        _Pragma("unroll")                                                     \
        for (int k = 0; k < 12; ++k) {                                        \
            int idx = l + k * 64;                                             \
            float v = ((nv) == 0) ? xr[k].x : ((nv) == 1) ? xr[k].y           \
                    : ((nv) == 2) ? xr[k].z : xr[k].w;                        \
            xSw[idx] = v;                                                     \
        }                                                                     \
        WAVEBAR();                                                            \
        half8 af[3];                                                          \
        _Pragma("unroll")                                                     \
        for (int ks = 0; ks < 3; ++ks) {                                      \
            int f0 = ks * 32 + hi * 8;                                        \
            int cc = (f0 < 48) ? f0 : f0 - 48;                                \
            float4 a  = *(const float4*)&xSw[row16 * 48 + cc];                \
            float4 b2 = *(const float4*)&xSw[row16 * 48 + cc + 4];            \
            float vv[8] = {a.x, a.y, a.z, a.w, b2.x, b2.y, b2.z, b2.w};       \
            bool inv = (f0 >= 48);                                            \
            half8 hv;                                                         \
            _Pragma("unroll")                                                 \
            for (int j = 0; j < 8; ++j)                                       \
                hv[j] = (_Float16)(inv ? (1.f - vv[j]) : vv[j]);              \
            af[ks] = hv;                                                      \
        }                                                                     \
        WAVEBAR();                                                            \
        CHUNKD((nv) * 5 + 0, W0)                                              \
        CHUNKD((nv) * 5 + 1, W1)                                              \
        CHUNKD((nv) * 5 + 2, W2)                                              \
        CHUNKD((nv) * 5 + 3, W3)                                              \
        CHUNKD((nv) * 5 + 4, W4)                                              \
        _Pragma("unroll")                                                     \
        for (int j = 0; j < 5; ++j) {                                         \
            lw[bQ * 20 + mh * 5 + j] = lacc[j]; lacc[j] = 0.f;                \
        }                                                                     \
        WAVEBAR();                                                            \
    }

__global__ __launch_bounds__(256, 2)
void fused1_kernel(const float* __restrict__ x, const float* __restrict__ cores1,
                   const float* __restrict__ label1,
                   const float* __restrict__ cores2, const float* __restrict__ cores3,
                   const float* __restrict__ label2, const float* __restrict__ label3,
                   float* __restrict__ z1, float* __restrict__ gs, float* __restrict__ gq,
                   _Float16* __restrict__ Wh2, _Float16* __restrict__ Wh3,
                   float* __restrict__ lv2, float* __restrict__ lv3,
                   float* __restrict__ gzero)
{
    __shared__ __align__(16) float xS[4 * 768];           // 12288 B
    __shared__ __align__(16) _Float16 Fbuf[2][7680];      // 30720 B
    __shared__ __align__(16) float MchunkS[4 * 16 * 84];  // 21504 B
    __shared__ __align__(16) float leftS[4 * 320];        // 5120 B
    __shared__ __align__(16) float labvS[400];            // 1600 B

    const int tid  = threadIdx.x;
    const int bid  = blockIdx.x;
    const int orig = bid & 255;
    const int bh   = bid >> 8;                            // batch half; +256 keeps XCD
    const int p    = (orig & 7) * 32 + (orig >> 3);       // XCD swizzle, bijective
    const int wv   = tid >> 6, l = tid & 63;              // 4 waves
    float* xSw = xS + wv * 768;
    float* Mw  = MchunkS + wv * 1344;
    float* lw  = leftS + wv * 320;
    const int row16 = l & 15, hi = l >> 4;
    const int bQ = l >> 2,   mh = l & 3;
    const int bg = bh * 64;
    const int hh  = (p >> 7) * 16 + ((p >> 2) & 15);
    const int ww0 = ((p >> 6) & 1) * 16 + (p & 3) * 4;

    // x preload: wave-private 16 rows x 48 c; one float4 = all 4 sites
    float4 xr[12];
    #pragma unroll
    for (int k = 0; k < 12; ++k) {
        int idx = l + k * 64;
        int br = idx / 48, c = idx - br * 48;
        xr[k] = *(const float4*)(x + (((size_t)((bg + wv * 16 + br) * 48 + c)) << 10)
                                   + hh * 32 + ww0);
    }

    // chunk-invariant scatter addresses (verified bijection, F=96)
    int sAddr[8][4];
    #pragma unroll
    for (int k = 0; k < 8; ++k) {
        int i4 = tid + k * 256;
        if (i4 < 1920) {
            #pragma unroll
            for (int t = 0; t < 4; ++t) {
                int e = i4 * 4 + t;
                int v = e % 20;
                int r = e / 20;
                int f = r % 96;
                int ul = r / 96;
                int c = ul * 20 + v;
                sAddr[k][t] = (((f >> 5) * 5 + (c >> 4)) * 64 +
                               ((f >> 3) & 3) * 16 + (c & 15)) * 8 + (f & 7);
            }
        }
    }

    #pragma unroll
    for (int j = 0; j < 5; ++j) lw[bQ * 20 + mh * 5 + j] = VB;
    WAVEBAR();

    float lacc[5] = {0.f, 0.f, 0.f, 0.f, 0.f};
    float4 wrA[8], wrB[8];
    const float* wbase = cores1 + (size_t)p * 153600;

    _Float16* Fcur = &Fbuf[0][0];
    _Float16* Fnxt = &Fbuf[1][0];

    // prologue: c0 -> Fcur; preload c1 (wrA) and c2 (wrB)
    LOADW(wrA, 0)
    SCATW(wrA, Fcur)
    LOADW(wrA, 1)
    LOADW(wrB, 2)
    BARRIER_LGKM();

    // labv1 inline (ordered before epilogue by SITE barriers)
    for (int i = tid; i < 400; i += 256) {
        const float* lb = label1 + (size_t)p * 8000 + i * 20;
        float s = 0.f;
        #pragma unroll
        for (int vv = 0; vv < 20; ++vv) s += lb[vv];
        labvS[i] = s * VB;
    }

    SITE(0, wrA, wrB, wrA, wrB, wrA)
    SITE(1, wrB, wrA, wrB, wrA, wrB)
    SITE(2, wrA, wrB, wrA, wrB, wrA)
    SITE(3, wrB, wrA, wrB, wrA, wrB)

    // epilogue: labv matvec + z1 + BN atomic sums (verified R5-R12 path)
    float yv[5] = {0.f, 0.f, 0.f, 0.f, 0.f};
    #pragma unroll
    for (int u = 0; u < 20; ++u) {
        float lu = lw[bQ * 20 + u];
        #pragma unroll
        for (int j = 0; j < 5; ++j) yv[j] += lu * labvS[u * 20 + mh * 5 + j];
    }
    float s = 0.f, s2 = 0.f;
    #pragma unroll
    for (int j = 0; j < 5; ++j) {
        z1[(size_t)(bg + wv * 16 + bQ) * 5120 + p * 20 + mh * 5 + j] = yv[j];
        s += yv[j]; s2 += yv[j] * yv[j];
    }
    #pragma unroll
    for (int off = 32; off > 0; off >>= 1) {
        s  += __shfl_down(s, off);
        s2 += __shfl_down(s2, off);
    }
    if (l == 0) { atomicAdd(&gs[p], s); atomicAdd(&gq[p], s2); }

    // ---- tail: prep work, grid-strided (fills block-finish skew) ----
    __syncthreads();                      // xS dead -> reuse as fragS
    _Float16* fragS = (_Float16*)xS;      // 10240 B needed

    #pragma unroll
    for (int k = 0; k < 3; ++k) {
        int i = tid + k * 256;
        if (i < 640) ((uint4*)fragS)[i] = (uint4){0, 0, 0, 0};
    }
    __syncthreads();

    for (int slab = bid; slab < 1600; slab += 512) {
        const float* src;
        _Float16* dst;
        if (slab < 1280) { src = cores2 + (size_t)slab * 3200;          dst = Wh2 + (size_t)slab * 5120; }
        else             { src = cores3 + (size_t)(slab - 1280) * 3200; dst = Wh3 + (size_t)(slab - 1280) * 5120; }
        #pragma unroll
        for (int k = 0; k < 4; ++k) {
            int i4 = tid + k * 256;
            if (i4 < 800) {
                float4 w = *(const float4*)(src + i4 * 4);
                float vals[4] = {w.x, w.y, w.z, w.w};
                #pragma unroll
                for (int t = 0; t < 4; ++t) {
                    int e = i4 * 4 + t;
                    int v = e % 20;
                    int r = e / 20;
                    int f = r % 40;
                    int ul = r / 40;
                    int c = ul * 20 + v;
                    int addr = (((f >> 5) * 5 + (c >> 4)) * 64 +
                                ((f >> 3) & 3) * 16 + (c & 15)) * 8 + (f & 7);
                    fragS[addr] = (_Float16)vals[t];
                }
            }
        }
        __syncthreads();
        #pragma unroll
        for (int k = 0; k < 3; ++k) {
            int i = tid + k * 256;
            if (i < 640) ((uint4*)dst)[i] = ((const uint4*)fragS)[i];
        }
        __syncthreads();
    }

    // labv2/3 (blocks 0..79)
    if (bid < 80) {
        const float* lb;
        float* ov;
        if (bid < 64) { lb = label2 + (size_t)bid * 8000;        ov = lv2 + bid * 400; }
        else          { lb = label3 + (size_t)(bid - 64) * 8000; ov = lv3 + (bid - 64) * 400; }
        for (int i = tid; i < 400; i += 256) {
            const float4* sp = (const float4*)(lb + i * 20);
            float acc = 0.f;
            #pragma unroll
            for (int t = 0; t < 5; ++t) {
                float4 w = sp[t];
                acc += w.x + w.y + w.z + w.w;
            }
            ov[i] = acc * VB;
        }
    }
    // zero stage-2/3 BN atomic sums (gs2..gq3 = 160 floats)
    if (bid == 511 && tid < 160) gzero[tid] = 0.f;
}

// ---------------------------------------------------------------------------
// Fused stages 2 & 3 (byte-identical to verified R13/R16/R17/R18)
// ---------------------------------------------------------------------------
#define UCBODYN(ucv, CUR, NXT)                                                   \
    {                                                                            \
        if ((ucv) < 4) {                                                         \
            const _Float16* bptr = whp + (size_t)((ucv) + 1) * 5120;             \
            _Pragma("unroll")                                                    \
            for (int q = 0; q < 10; ++q)                                         \
                NXT[q] = *(const half8*)(bptr + (q * 64 + l) * 8);               \
        }                                                                        \
        f32x4 acc[5];                                                            \
        _Pragma("unroll")                                                        \
        for (int nt = 0; nt < 5; ++nt) acc[nt] = (f32x4){0.f, 0.f, 0.f, 0.f};    \
        _Pragma("unroll")                                                        \
        for (int ks = 0; ks < 2; ++ks) {                                         \
            _Pragma("unroll")                                                    \
            for (int nt = 0; nt < 5; ++nt)                                       \
                acc[nt] = __builtin_amdgcn_mfma_f32_16x16x32_f16(                \
                    af[ks], CUR[ks * 5 + nt], acc[nt], 0, 0, 0);                 \
        }                                                                        \
        _Pragma("unroll")                                                        \
        for (int nt = 0; nt < 5; ++nt) {                                         \
            _Pragma("unroll")                                                    \
            for (int r = 0; r < 4; ++r)                                          \
                Mw[(hi * 4 + r) * 84 + nt * 16 + row16] = acc[nt][r];            \
        }                                                                        \
        WAVEBAR();                                                               \
        _Pragma("unroll")                                                        \
        for (int ul = 0; ul < 4; ++ul) {                                         \
            float lvx = lw[bQ * 20 + (ucv) * 4 + ul];                            \
            _Pragma("unroll")                                                    \
            for (int j = 0; j < 5; ++j)                                          \
                lacc[j] += lvx * Mw[bQ * 84 + ul * 20 + mh * 5 + j];             \
        }                                                                        \
        WAVEBAR();                                                               \
    }

template <int STAGE>
__global__ __launch_bounds__(256, 2)
void stageN_kernel(const float* __restrict__ zin, const _Float16* __restrict__ Wh,
                   const float* __restrict__ labv,
                   const float* __restrict__ gsin, const float* __restrict__ gqin,
                   const float* __restrict__ gam,  const float* __restrict__ bet,
                   float* __restrict__ zout,
                   float* __restrict__ gsout, float* __restrict__ gqout)
{
    constexpr int ZIN  = (STAGE == 2) ? 5120 : 1280;
    constexpr int ZOUT = (STAGE == 2) ? 1280 : 320;
    constexpr int JUMP = (STAGE == 2) ? 256 : 64;

    __shared__ __align__(16) float zS[4 * 320];
    __shared__ float scS[4 * 20], shS[4 * 20];
    __shared__ __align__(16) float MchunkS[4 * 16 * 84];
    __shared__ __align__(16) float leftS[4 * 320];

    const int tid = threadIdx.x;
    const int p   = blockIdx.x;
    const int bh  = blockIdx.y;
    const int wv  = tid >> 6, l = tid & 63;
    float* zSw = zS + wv * 320;
    float* scw = scS + wv * 20;
    float* shw = shS + wv * 20;
    float* Mw  = MchunkS + wv * 1344;
    float* lw  = leftS + wv * 320;
    const int row16 = l & 15, hi = l >> 4;
    const int bQ = l >> 2,   mh = l & 3;
    const int bg = bh * 64;

    #pragma unroll
    for (int j = 0; j < 5; ++j) lw[bQ * 20 + mh * 5 + j] = VB;
    WAVEBAR();

    float lacc[5] = {0.f, 0.f, 0.f, 0.f, 0.f};

    #pragma unroll 1
    for (int n = 0; n < 4; ++n) {
        int hh, ww;
        if (STAGE == 2) { hh = (p >> 5) * 8 + ((p >> 1) & 7); ww = ((p >> 4) & 1) * 8 + (p & 1) * 4 + n; }
        else            { hh = (p >> 3) * 4 + (p & 3);        ww = ((p >> 2) & 1) * 4 + n; }
        const int oo = (STAGE == 2) ? (hh * 16 + ww) : (hh * 8 + ww);

        if (l < 20) {
            int ch = (l * JUMP + oo) / 20;
            float mean = gsin[ch] * (1.f / 2560.f);
            float var  = gqin[ch] * (1.f / 2560.f) - mean * mean;
            float rstd = rsqrtf(var + 1e-5f);
            float sc = gam[ch] * rstd;
            scw[l] = sc;
            shw[l] = bet[ch] - mean * sc;
        }
        WAVEBAR();
        #pragma unroll
        for (int q = 0; q < 5; ++q) {
            int d = hi * 5 + q;
            float zraw = zin[(size_t)(bg + wv * 16 + row16) * ZIN + d * JUMP + oo];
            zSw[row16 * 20 + d] = zraw * scw[d] + shw[d];
        }
        WAVEBAR();
        half8 af[2];
        #pragma unroll
        for (int ks = 0; ks < 2; ++ks) {
            int f0 = ks * 32 + hi * 8;
            half8 hv;
            #pragma unroll
            for (int j = 0; j < 8; ++j) {
                int f = f0 + j;
                float val;
                if (f < 20)      val = zSw[row16 * 20 + f];
                else if (f < 40) val = 1.f - zSw[row16 * 20 + f - 20];
                else             val = 0.f;
                hv[j] = (_Float16)val;
            }
            af[ks] = hv;
        }
        WAVEBAR();

        const _Float16* whp = Wh + (size_t)((p * 4 + n) * 5) * 5120;
        half8 bA[10], bB[10];
        {
            #pragma unroll
            for (int q = 0; q < 10; ++q) bA[q] = *(const half8*)(whp + (q * 64 + l) * 8);
        }
        UCBODYN(0, bA, bB)
        UCBODYN(1, bB, bA)
        UCBODYN(2, bA, bB)
        UCBODYN(3, bB, bA)
        UCBODYN(4, bA, bB)

        #pragma unroll
        for (int j = 0; j < 5; ++j) { lw[bQ * 20 + mh * 5 + j] = lacc[j]; lacc[j] = 0.f; }
        WAVEBAR();
    }

    const float* lvp = labv + p * 400;
    #pragma unroll
    for (int k = 0; k < 7; ++k) { int i = l + k * 64; if (i < 400) Mw[i] = lvp[i]; }
    WAVEBAR();
    float yv[5] = {0.f, 0.f, 0.f, 0.f, 0.f};
    #pragma unroll
    for (int u = 0; u < 20; ++u) {
        float lu = lw[bQ * 20 + u];
        #pragma unroll
        for (int j = 0; j < 5; ++j) yv[j] += lu * Mw[u * 20 + mh * 5 + j];
    }
    float s = 0.f, s2 = 0.f;
    #pragma unroll
    for (int j = 0; j < 5; ++j) {
        zout[(size_t)(bg + wv * 16 + bQ) * ZOUT + p * 20 + mh * 5 + j] = yv[j];
        s += yv[j]; s2 += yv[j] * yv[j];
    }
    #pragma unroll
    for (int off = 32; off > 0; off >>= 1) {
        s  += __shfl_down(s, off);
        s2 += __shfl_down(s2, off);
    }
    if ((tid & 63) == 0) {
        atomicAdd(&gsout[p], s);
        atomicAdd(&gqout[p], s2);
    }
}

// ---------------------------------------------------------------------------
// Final MPS (byte-identical to verified R13/R16/R17/R18)
// ---------------------------------------------------------------------------
__global__ __launch_bounds__(256, 4)
void final_kernel(const float* __restrict__ z3,
                  const float* __restrict__ coresF,
                  const float* __restrict__ labelF,
                  const float* __restrict__ g3,
                  const float* __restrict__ b3,
                  const float* __restrict__ gsum3,
                  const float* __restrict__ gsq3,
                  float* __restrict__ out)
{
    __shared__ __align__(16) float fS[16 * 40];
    __shared__ __align__(16) float MS[16 * 400];
    __shared__ float lvS[200];
    __shared__ float scS[16], shS[16];
    __shared__ float leftS[20];

    const int b   = blockIdx.x;
    const int tid = threadIdx.x;

    if (tid < 16) {
        float mean = gsum3[tid] * (1.f / 2560.f);
        float var  = gsq3[tid] * (1.f / 2560.f) - mean * mean;
        float rstd = rsqrtf(var + 1e-5f);
        float sc   = g3[tid] * rstd;
        scS[tid] = sc;
        shS[tid] = b3[tid] - mean * sc;
    }
    __syncthreads();

    for (int i = tid; i < 640; i += 256) {
        int n = i / 40, f = i - n * 40;
        float raw = z3[(size_t)b * 320 + n * 20 + (f % 20)];
        float val = raw * scS[n] + shS[n];
        fS[i] = (f < 20) ? val : (1.f - val);
    }
    for (int i = tid; i < 200; i += 256) {
        int u = i / 10, o = i - u * 10;
        const float* lb = labelF + (size_t)(u * 10 + o) * 20;
        float s = 0.f;
        #pragma unroll
        for (int vv = 0; vv < 20; ++vv) s += lb[vv];
        lvS[i] = s * VB;
    }
    __syncthreads();

    for (int i = tid; i < 6400; i += 256) {
        int n = i / 400, uv = i - n * 400;
        int u = uv / 20, v = uv - u * 20;
        const float* wb = coresF + ((size_t)(n * 20 + u) * 40) * 20 + v;
        const float* fb = fS + n * 40;
        float acc = 0.f;
        #pragma unroll
        for (int f = 0; f < 40; ++f) acc += fb[f] * wb[f * 20];
        MS[i] = acc;
    }
    __syncthreads();

    if (tid < 64) {
        if (tid < 20) leftS[tid] = VB;
        WAVEBAR();
        #pragma unroll 1
        for (int n = 0; n < 16; ++n) {
            float tmp = 0.f;
            if (tid < 20) {
                #pragma unroll
                for (int u = 0; u < 20; ++u) tmp += leftS[u] * MS[n * 400 + u * 20 + tid];
            }
            WAVEBAR();
            if (tid < 20) leftS[tid] = tmp;
            WAVEBAR();
        }
        if (tid < 10) {
            float s = 0.f;
            #pragma unroll
            for (int u = 0; u < 20; ++u) s += leftS[u] * lvS[u * 10 + tid];
            out[b * 10 + tid] = s;
        }
    }
}

// ---------------------------------------------------------------------------
extern "C" void kernel_launch(void* const* d_in, const int* in_sizes, int n_in,
                              void* d_out, int out_size, void* d_ws, size_t ws_size,
                              hipStream_t stream)
{
    const float* x      = (const float*)d_in[0];
    const float* cores1 = (const float*)d_in[1];
    const float* label1 = (const float*)d_in[2];
    const float* g1     = (const float*)d_in[3];
    const float* b1     = (const float*)d_in[4];
    const float* cores2 = (const float*)d_in[5];
    const float* label2 = (const float*)d_in[6];
    const float* g2     = (const float*)d_in[7];
    const float* b2     = (const float*)d_in[8];
    const float* cores3 = (const float*)d_in[9];
    const float* label3 = (const float*)d_in[10];
    const float* g3     = (const float*)d_in[11];
    const float* b3     = (const float*)d_in[12];
    const float* coresF = (const float*)d_in[13];
    const float* labelF = (const float*)d_in[14];

    float* ws  = (float*)d_ws;
    float* z1  = ws + Z1_OFF;
    float* z2  = ws + Z2_OFF;
    float* z3  = ws + Z3_OFF;
    float* gs1 = ws + GS1_OFF; float* gq1 = ws + GQ1_OFF;
    float* gs2 = ws + GS2_OFF; float* gq2 = ws + GQ2_OFF;
    float* gs3 = ws + GS3_OFF; float* gq3 = ws + GQ3_OFF;
    float* lv2 = ws + LV2_OFF;
    float* lv3 = ws + LV3_OFF;
    _Float16* Wh2 = (_Float16*)(ws + WH2_OFF);
    _Float16* Wh3 = (_Float16*)(ws + WH3_OFF);

    // zero stage-1 BN atomic sums (gs1..gq1 = 512 floats, contiguous)
    hipMemsetAsync(gs1, 0, 512 * sizeof(float), stream);

    fused1_kernel<<<512, 256, 0, stream>>>(x, cores1, label1,
                                           cores2, cores3, label2, label3,
                                           z1, gs1, gq1,
                                           Wh2, Wh3, lv2, lv3, gs2);
    stageN_kernel<2><<<dim3(64, 2), 256, 0, stream>>>(z1, Wh2, lv2, gs1, gq1, g1, b1,
                                                      z2, gs2, gq2);
    stageN_kernel<3><<<dim3(16, 2), 256, 0, stream>>>(z2, Wh3, lv3, gs2, gq2, g2, b2,
                                                      z3, gs3, gq3);
    final_kernel<<<128, 256, 0, stream>>>(z3, coresF, labelF, g3, b3,
                                          gs3, gq3, (float*)d_out);
}

// Round 20
// 107.443 us; speedup vs baseline: 1.8139x; 1.8139x over previous
//
#include <hip/hip_runtime.h>

#define VB 0.22360679774997896f  // 20^-0.5

typedef __attribute__((ext_vector_type(8))) _Float16 half8;
typedef __attribute__((ext_vector_type(4))) float f32x4;

// workspace float offsets (R13/R16 layout)
#define Z1_OFF   0
#define Z2_OFF   655360
#define Z3_OFF   819200
#define GS1_OFF  860160
#define GQ1_OFF  860416
#define GS2_OFF  860672
#define GQ2_OFF  860736
#define GS3_OFF  860800
#define GQ3_OFF  860816
#define LV2_OFF  963232    // 64*400
#define LV3_OFF  988832    // 16*400
#define WH2_OFF  995232    // 6553600 halfs
#define WH3_OFF  4272032   // 1638400 halfs

#define WAVEBAR() __builtin_amdgcn_wave_barrier()

// LDS-only barrier: orders ds ops across the block WITHOUT draining vmcnt
// (T4 counted-wait pattern; global prefetch loads stay in flight).
#define BARRIER_LGKM()                                        \
    asm volatile("s_waitcnt lgkmcnt(0)" ::: "memory");        \
    __builtin_amdgcn_sched_barrier(0);                        \
    __builtin_amdgcn_s_barrier();

// ---------------------------------------------------------------------------
// Fused stage 1 (verified best, R18 bench: 107.5 us total).
// 256 blocks x 512 thr; 8 waves x 16 batch rows; cores1 read once;
// 3-deep W prefetch; lgkm-only chunk barriers. Tail: wconv2/3 + labv2/3.
// ---------------------------------------------------------------------------
#define LOADW(W, ci)                                                          \
    {                                                                         \
        const float* wp_ = wbase + (size_t)(ci) * 7680;                       \
        _Pragma("unroll")                                                     \
        for (int k = 0; k < 4; ++k) {                                         \
            int i4 = tid + k * 512;                                           \
            if (i4 < 1920) W[k] = *(const float4*)(wp_ + i4 * 4);             \
        }                                                                     \
    }

#define SCATW(W, DST)                                                         \
    {                                                                         \
        _Pragma("unroll")                                                     \
        for (int k = 0; k < 4; ++k) {                                         \
            int i4 = tid + k * 512;                                           \
            if (i4 < 1920) {                                                  \
                float vals[4] = {W[k].x, W[k].y, W[k].z, W[k].w};             \
                _Pragma("unroll")                                             \
                for (int t = 0; t < 4; ++t)                                   \
                    DST[sAddr[k][t]] = (_Float16)vals[t];                     \
            }                                                                 \
        }                                                                     \
    }

#define CHUNKD(ci, W)                                                         \
    {                                                                         \
        f32x4 acc[5];                                                         \
        _Pragma("unroll")                                                     \
        for (int nt = 0; nt < 5; ++nt) acc[nt] = (f32x4){0.f, 0.f, 0.f, 0.f};\
        _Pragma("unroll")                                                     \
        for (int ks = 0; ks < 3; ++ks) {                                      \
            _Pragma("unroll")                                                 \
            for (int nt = 0; nt < 5; ++nt) {                                  \
                half8 bf = *(const half8*)&Fcur[((ks * 5 + nt) * 64 + l) * 8];\
                acc[nt] = __builtin_amdgcn_mfma_f32_16x16x32_f16(             \
                    af[ks], bf, acc[nt], 0, 0, 0);                            \
            }                                                                 \
        }                                                                     \
        _Pragma("unroll")                                                     \
        for (int nt = 0; nt < 5; ++nt) {                                      \
            _Pragma("unroll")                                                 \
            for (int r = 0; r < 4; ++r)                                       \
                Mw[(hi * 4 + r) * 84 + nt * 16 + row16] = acc[nt][r];         \
        }                                                                     \
        WAVEBAR();                                                            \
        _Pragma("unroll")                                                     \
        for (int ul = 0; ul < 4; ++ul) {                                      \
            float lvx = lw[bQ * 20 + ((ci) % 5) * 4 + ul];                    \
            _Pragma("unroll")                                                 \
            for (int j = 0; j < 5; ++j)                                       \
                lacc[j] += lvx * Mw[bQ * 84 + ul * 20 + mh * 5 + j];          \
        }                                                                     \
        WAVEBAR();                                                            \
        BARRIER_LGKM();                                                       \
        if ((ci) < 19) { SCATW(W, Fnxt) }                                     \
        BARRIER_LGKM();                                                       \
        { _Float16* t_ = Fcur; Fcur = Fnxt; Fnxt = t_; }                      \
        if ((ci) <= 16) { LOADW(W, (ci) + 3) }                                \
    }

#define SITE(nv, W0, W1, W2, W3, W4)                                          \
    {                                                                         \
        _Pragma("unroll")                                                     \
        for (int k = 0; k < 12; ++k) {                                        \
            int idx = l + k * 64;                                             \
            float v = ((nv) == 0) ? xr[k].x : ((nv) == 1) ? xr[k].y           \
                    : ((nv) == 2) ? xr[k].z : xr[k].w;                        \
            xSw[idx] = v;                                                     \
        }                                                                     \
        WAVEBAR();                                                            \
        half8 af[3];                                                          \
        _Pragma("unroll")                                                     \
        for (int ks = 0; ks < 3; ++ks) {                                      \
            int f0 = ks * 32 + hi * 8;                                        \
            int cc = (f0 < 48) ? f0 : f0 - 48;                                \
            float4 a  = *(const float4*)&xSw[row16 * 48 + cc];                \
            float4 b2 = *(const float4*)&xSw[row16 * 48 + cc + 4];            \
            float vv[8] = {a.x, a.y, a.z, a.w, b2.x, b2.y, b2.z, b2.w};       \
            bool inv = (f0 >= 48);                                            \
            half8 hv;                                                         \
            _Pragma("unroll")                                                 \
            for (int j = 0; j < 8; ++j)                                       \
                hv[j] = (_Float16)(inv ? (1.f - vv[j]) : vv[j]);              \
            af[ks] = hv;                                                      \
        }                                                                     \
        WAVEBAR();                                                            \
        CHUNKD((nv) * 5 + 0, W0)                                              \
        CHUNKD((nv) * 5 + 1, W1)                                              \
        CHUNKD((nv) * 5 + 2, W2)                                              \
        CHUNKD((nv) * 5 + 3, W3)                                              \
        CHUNKD((nv) * 5 + 4, W4)                                              \
        _Pragma("unroll")                                                     \
        for (int j = 0; j < 5; ++j) {                                         \
            lw[bQ * 20 + mh * 5 + j] = lacc[j]; lacc[j] = 0.f;                \
        }                                                                     \
        WAVEBAR();                                                            \
    }

__global__ __launch_bounds__(512, 2)
void fused1_kernel(const float* __restrict__ x, const float* __restrict__ cores1,
                   const float* __restrict__ label1,
                   const float* __restrict__ cores2, const float* __restrict__ cores3,
                   const float* __restrict__ label2, const float* __restrict__ label3,
                   float* __restrict__ z1, float* __restrict__ gs, float* __restrict__ gq,
                   _Float16* __restrict__ Wh2, _Float16* __restrict__ Wh3,
                   float* __restrict__ lv2, float* __restrict__ lv3,
                   float* __restrict__ gzero)
{
    __shared__ __align__(16) float xS[8 * 768];           // 24576 B
    __shared__ __align__(16) _Float16 Fbuf[2][7680];      // 30720 B
    __shared__ __align__(16) float MchunkS[8 * 16 * 84];  // 43008 B
    __shared__ __align__(16) float leftS[8 * 320];        // 10240 B
    __shared__ __align__(16) float labvS[400];            // 1600 B
    __shared__ float redS[16];

    const int tid = threadIdx.x;
    const int bid = blockIdx.x;
    const int p   = (bid & 7) * 32 + (bid >> 3);          // XCD swizzle, bijective
    const int wv  = tid >> 6, l = tid & 63;
    float* xSw = xS + wv * 768;
    float* Mw  = MchunkS + wv * 1344;
    float* lw  = leftS + wv * 320;
    const int row16 = l & 15, hi = l >> 4;
    const int bQ = l >> 2,   mh = l & 3;
    const int hh  = (p >> 7) * 16 + ((p >> 2) & 15);
    const int ww0 = ((p >> 6) & 1) * 16 + (p & 3) * 4;

    // x preload: wave-private 16 rows x 48 c; one float4 = all 4 sites
    float4 xr[12];
    #pragma unroll
    for (int k = 0; k < 12; ++k) {
        int idx = l + k * 64;
        int br = idx / 48, c = idx - br * 48;
        xr[k] = *(const float4*)(x + (((size_t)((wv * 16 + br) * 48 + c)) << 10)
                                   + hh * 32 + ww0);
    }

    // chunk-invariant scatter addresses (verified bijection, F=96)
    int sAddr[4][4];
    #pragma unroll
    for (int k = 0; k < 4; ++k) {
        int i4 = tid + k * 512;
        if (i4 < 1920) {
            #pragma unroll
            for (int t = 0; t < 4; ++t) {
                int e = i4 * 4 + t;
                int v = e % 20;
                int r = e / 20;
                int f = r % 96;
                int ul = r / 96;
                int c = ul * 20 + v;
                sAddr[k][t] = (((f >> 5) * 5 + (c >> 4)) * 64 +
                               ((f >> 3) & 3) * 16 + (c & 15)) * 8 + (f & 7);
            }
        }
    }

    #pragma unroll
    for (int j = 0; j < 5; ++j) lw[bQ * 20 + mh * 5 + j] = VB;
    WAVEBAR();

    float lacc[5] = {0.f, 0.f, 0.f, 0.f, 0.f};
    float4 wrA[4], wrB[4];
    const float* wbase = cores1 + (size_t)p * 153600;

    _Float16* Fcur = &Fbuf[0][0];
    _Float16* Fnxt = &Fbuf[1][0];

    // prologue: c0 -> Fcur; preload c1 (wrA) and c2 (wrB)
    LOADW(wrA, 0)
    SCATW(wrA, Fcur)
    LOADW(wrA, 1)
    LOADW(wrB, 2)
    BARRIER_LGKM();

    // labv1 inline (ordered before epilogue by SITE barriers)
    if (tid < 400) {
        const float* lb = label1 + (size_t)p * 8000 + tid * 20;
        float s = 0.f;
        #pragma unroll
        for (int vv = 0; vv < 20; ++vv) s += lb[vv];
        labvS[tid] = s * VB;
    }

    SITE(0, wrA, wrB, wrA, wrB, wrA)
    SITE(1, wrB, wrA, wrB, wrA, wrB)
    SITE(2, wrA, wrB, wrA, wrB, wrA)
    SITE(3, wrB, wrA, wrB, wrA, wrB)

    // epilogue: labv matvec + z1 + block-local BN
    float yv[5] = {0.f, 0.f, 0.f, 0.f, 0.f};
    #pragma unroll
    for (int u = 0; u < 20; ++u) {
        float lu = lw[bQ * 20 + u];
        #pragma unroll
        for (int j = 0; j < 5; ++j) yv[j] += lu * labvS[u * 20 + mh * 5 + j];
    }
    float s = 0.f, s2 = 0.f;
    #pragma unroll
    for (int j = 0; j < 5; ++j) {
        z1[(size_t)(wv * 16 + bQ) * 5120 + p * 20 + mh * 5 + j] = yv[j];
        s += yv[j]; s2 += yv[j] * yv[j];
    }
    #pragma unroll
    for (int off = 32; off > 0; off >>= 1) {
        s  += __shfl_down(s, off);
        s2 += __shfl_down(s2, off);
    }
    if (l == 0) { redS[wv] = s; redS[8 + wv] = s2; }
    __syncthreads();
    if (tid == 0) {
        float S = 0.f, Q = 0.f;
        #pragma unroll
        for (int w2 = 0; w2 < 8; ++w2) { S += redS[w2]; Q += redS[8 + w2]; }
        gs[p] = S; gq[p] = Q;
    }

    // ---- tail: prep work, grid-strided (fills block-finish skew) ----
    __syncthreads();                      // xS dead -> reuse as fragS
    _Float16* fragS = (_Float16*)xS;      // 10240 B needed

    // zero fragS once (pad addresses are slab-invariant; scatter covers f<40)
    #pragma unroll
    for (int k = 0; k < 2; ++k) {
        int i = tid + k * 512;
        if (i < 640) ((uint4*)fragS)[i] = (uint4){0, 0, 0, 0};
    }
    __syncthreads();

    for (int slab = bid; slab < 1600; slab += 256) {
        const float* src;
        _Float16* dst;
        if (slab < 1280) { src = cores2 + (size_t)slab * 3200;          dst = Wh2 + (size_t)slab * 5120; }
        else             { src = cores3 + (size_t)(slab - 1280) * 3200; dst = Wh3 + (size_t)(slab - 1280) * 5120; }
        #pragma unroll
        for (int k = 0; k < 2; ++k) {
            int i4 = tid + k * 512;
            if (i4 < 800) {
                float4 w = *(const float4*)(src + i4 * 4);
                float vals[4] = {w.x, w.y, w.z, w.w};
                #pragma unroll
                for (int t = 0; t < 4; ++t) {
                    int e = i4 * 4 + t;
                    int v = e % 20;
                    int r = e / 20;
                    int f = r % 40;
                    int ul = r / 40;
                    int c = ul * 20 + v;
                    int addr = (((f >> 5) * 5 + (c >> 4)) * 64 +
                                ((f >> 3) & 3) * 16 + (c & 15)) * 8 + (f & 7);
                    fragS[addr] = (_Float16)vals[t];
                }
            }
        }
        __syncthreads();
        #pragma unroll
        for (int k = 0; k < 2; ++k) {
            int i = tid + k * 512;
            if (i < 640) ((uint4*)dst)[i] = ((const uint4*)fragS)[i];
        }
        __syncthreads();                  // writes done before next scatter
    }

    // labv2/3 (blocks 0..79, one each)
    if (bid < 80) {
        const float* lb;
        float* ov;
        if (bid < 64) { lb = label2 + (size_t)bid * 8000;        ov = lv2 + bid * 400; }
        else          { lb = label3 + (size_t)(bid - 64) * 8000; ov = lv3 + (bid - 64) * 400; }
        if (tid < 400) {
            const float4* sp = (const float4*)(lb + tid * 20);
            float acc = 0.f;
            #pragma unroll
            for (int t = 0; t < 5; ++t) {
                float4 w = sp[t];
                acc += w.x + w.y + w.z + w.w;
            }
            ov[tid] = acc * VB;
        }
    }
    // zero stage-2/3 BN atomic sums (gs2..gq3 = 160 floats)
    if (bid == 255 && tid < 160) gzero[tid] = 0.f;
}

// ---------------------------------------------------------------------------
// Fused stages 2 & 3 (byte-identical to verified R13/R16/R17/R18)
// ---------------------------------------------------------------------------
#define UCBODYN(ucv, CUR, NXT)                                                   \
    {                                                                            \
        if ((ucv) < 4) {                                                         \
            const _Float16* bptr = whp + (size_t)((ucv) + 1) * 5120;             \
            _Pragma("unroll")                                                    \
            for (int q = 0; q < 10; ++q)                                         \
                NXT[q] = *(const half8*)(bptr + (q * 64 + l) * 8);               \
        }                                                                        \
        f32x4 acc[5];                                                            \
        _Pragma("unroll")                                                        \
        for (int nt = 0; nt < 5; ++nt) acc[nt] = (f32x4){0.f, 0.f, 0.f, 0.f};    \
        _Pragma("unroll")                                                        \
        for (int ks = 0; ks < 2; ++ks) {                                         \
            _Pragma("unroll")                                                    \
            for (int nt = 0; nt < 5; ++nt)                                       \
                acc[nt] = __builtin_amdgcn_mfma_f32_16x16x32_f16(                \
                    af[ks], CUR[ks * 5 + nt], acc[nt], 0, 0, 0);                 \
        }                                                                        \
        _Pragma("unroll")                                                        \
        for (int nt = 0; nt < 5; ++nt) {                                         \
            _Pragma("unroll")                                                    \
            for (int r = 0; r < 4; ++r)                                          \
                Mw[(hi * 4 + r) * 84 + nt * 16 + row16] = acc[nt][r];            \
        }                                                                        \
        WAVEBAR();                                                               \
        _Pragma("unroll")                                                        \
        for (int ul = 0; ul < 4; ++ul) {                                         \
            float lvx = lw[bQ * 20 + (ucv) * 4 + ul];                            \
            _Pragma("unroll")                                                    \
            for (int j = 0; j < 5; ++j)                                          \
                lacc[j] += lvx * Mw[bQ * 84 + ul * 20 + mh * 5 + j];             \
        }                                                                        \
        WAVEBAR();                                                               \
    }

template <int STAGE>
__global__ __launch_bounds__(256, 2)
void stageN_kernel(const float* __restrict__ zin, const _Float16* __restrict__ Wh,
                   const float* __restrict__ labv,
                   const float* __restrict__ gsin, const float* __restrict__ gqin,
                   const float* __restrict__ gam,  const float* __restrict__ bet,
                   float* __restrict__ zout,
                   float* __restrict__ gsout, float* __restrict__ gqout)
{
    constexpr int ZIN  = (STAGE == 2) ? 5120 : 1280;
    constexpr int ZOUT = (STAGE == 2) ? 1280 : 320;
    constexpr int JUMP = (STAGE == 2) ? 256 : 64;

    __shared__ __align__(16) float zS[4 * 320];
    __shared__ float scS[4 * 20], shS[4 * 20];
    __shared__ __align__(16) float MchunkS[4 * 16 * 84];
    __shared__ __align__(16) float leftS[4 * 320];

    const int tid = threadIdx.x;
    const int p   = blockIdx.x;
    const int bh  = blockIdx.y;
    const int wv  = tid >> 6, l = tid & 63;
    float* zSw = zS + wv * 320;
    float* scw = scS + wv * 20;
    float* shw = shS + wv * 20;
    float* Mw  = MchunkS + wv * 1344;
    float* lw  = leftS + wv * 320;
    const int row16 = l & 15, hi = l >> 4;
    const int bQ = l >> 2,   mh = l & 3;
    const int bg = bh * 64;

    #pragma unroll
    for (int j = 0; j < 5; ++j) lw[bQ * 20 + mh * 5 + j] = VB;
    WAVEBAR();

    float lacc[5] = {0.f, 0.f, 0.f, 0.f, 0.f};

    #pragma unroll 1
    for (int n = 0; n < 4; ++n) {
        int hh, ww;
        if (STAGE == 2) { hh = (p >> 5) * 8 + ((p >> 1) & 7); ww = ((p >> 4) & 1) * 8 + (p & 1) * 4 + n; }
        else            { hh = (p >> 3) * 4 + (p & 3);        ww = ((p >> 2) & 1) * 4 + n; }
        const int oo = (STAGE == 2) ? (hh * 16 + ww) : (hh * 8 + ww);

        if (l < 20) {
            int ch = (l * JUMP + oo) / 20;
            float mean = gsin[ch] * (1.f / 2560.f);
            float var  = gqin[ch] * (1.f / 2560.f) - mean * mean;
            float rstd = rsqrtf(var + 1e-5f);
            float sc = gam[ch] * rstd;
            scw[l] = sc;
            shw[l] = bet[ch] - mean * sc;
        }
        WAVEBAR();
        #pragma unroll
        for (int q = 0; q < 5; ++q) {
            int d = hi * 5 + q;
            float zraw = zin[(size_t)(bg + wv * 16 + row16) * ZIN + d * JUMP + oo];
            zSw[row16 * 20 + d] = zraw * scw[d] + shw[d];
        }
        WAVEBAR();
        half8 af[2];
        #pragma unroll
        for (int ks = 0; ks < 2; ++ks) {
            int f0 = ks * 32 + hi * 8;
            half8 hv;
            #pragma unroll
            for (int j = 0; j < 8; ++j) {
                int f = f0 + j;
                float val;
                if (f < 20)      val = zSw[row16 * 20 + f];
                else if (f < 40) val = 1.f - zSw[row16 * 20 + f - 20];
                else             val = 0.f;
                hv[j] = (_Float16)val;
            }
            af[ks] = hv;
        }
        WAVEBAR();

        const _Float16* whp = Wh + (size_t)((p * 4 + n) * 5) * 5120;
        half8 bA[10], bB[10];
        {
            #pragma unroll
            for (int q = 0; q < 10; ++q) bA[q] = *(const half8*)(whp + (q * 64 + l) * 8);
        }
        UCBODYN(0, bA, bB)
        UCBODYN(1, bB, bA)
        UCBODYN(2, bA, bB)
        UCBODYN(3, bB, bA)
        UCBODYN(4, bA, bB)

        #pragma unroll
        for (int j = 0; j < 5; ++j) { lw[bQ * 20 + mh * 5 + j] = lacc[j]; lacc[j] = 0.f; }
        WAVEBAR();
    }

    const float* lvp = labv + p * 400;
    #pragma unroll
    for (int k = 0; k < 7; ++k) { int i = l + k * 64; if (i < 400) Mw[i] = lvp[i]; }
    WAVEBAR();
    float yv[5] = {0.f, 0.f, 0.f, 0.f, 0.f};
    #pragma unroll
    for (int u = 0; u < 20; ++u) {
        float lu = lw[bQ * 20 + u];
        #pragma unroll
        for (int j = 0; j < 5; ++j) yv[j] += lu * Mw[u * 20 + mh * 5 + j];
    }
    float s = 0.f, s2 = 0.f;
    #pragma unroll
    for (int j = 0; j < 5; ++j) {
        zout[(size_t)(bg + wv * 16 + bQ) * ZOUT + p * 20 + mh * 5 + j] = yv[j];
        s += yv[j]; s2 += yv[j] * yv[j];
    }
    #pragma unroll
    for (int off = 32; off > 0; off >>= 1) {
        s  += __shfl_down(s, off);
        s2 += __shfl_down(s2, off);
    }
    if ((tid & 63) == 0) {
        atomicAdd(&gsout[p], s);
        atomicAdd(&gqout[p], s2);
    }
}

// ---------------------------------------------------------------------------
// Final MPS (byte-identical to verified R13/R16/R17/R18)
// ---------------------------------------------------------------------------
__global__ __launch_bounds__(256, 4)
void final_kernel(const float* __restrict__ z3,
                  const float* __restrict__ coresF,
                  const float* __restrict__ labelF,
                  const float* __restrict__ g3,
                  const float* __restrict__ b3,
                  const float* __restrict__ gsum3,
                  const float* __restrict__ gsq3,
                  float* __restrict__ out)
{
    __shared__ __align__(16) float fS[16 * 40];
    __shared__ __align__(16) float MS[16 * 400];
    __shared__ float lvS[200];
    __shared__ float scS[16], shS[16];
    __shared__ float leftS[20];

    const int b   = blockIdx.x;
    const int tid = threadIdx.x;

    if (tid < 16) {
        float mean = gsum3[tid] * (1.f / 2560.f);
        float var  = gsq3[tid] * (1.f / 2560.f) - mean * mean;
        float rstd = rsqrtf(var + 1e-5f);
        float sc   = g3[tid] * rstd;
        scS[tid] = sc;
        shS[tid] = b3[tid] - mean * sc;
    }
    __syncthreads();

    for (int i = tid; i < 640; i += 256) {
        int n = i / 40, f = i - n * 40;
        float raw = z3[(size_t)b * 320 + n * 20 + (f % 20)];
        float val = raw * scS[n] + shS[n];
        fS[i] = (f < 20) ? val : (1.f - val);
    }
    for (int i = tid; i < 200; i += 256) {
        int u = i / 10, o = i - u * 10;
        const float* lb = labelF + (size_t)(u * 10 + o) * 20;
        float s = 0.f;
        #pragma unroll
        for (int vv = 0; vv < 20; ++vv) s += lb[vv];
        lvS[i] = s * VB;
    }
    __syncthreads();

    for (int i = tid; i < 6400; i += 256) {
        int n = i / 400, uv = i - n * 400;
        int u = uv / 20, v = uv - u * 20;
        const float* wb = coresF + ((size_t)(n * 20 + u) * 40) * 20 + v;
        const float* fb = fS + n * 40;
        float acc = 0.f;
        #pragma unroll
        for (int f = 0; f < 40; ++f) acc += fb[f] * wb[f * 20];
        MS[i] = acc;
    }
    __syncthreads();

    if (tid < 64) {
        if (tid < 20) leftS[tid] = VB;
        WAVEBAR();
        #pragma unroll 1
        for (int n = 0; n < 16; ++n) {
            float tmp = 0.f;
            if (tid < 20) {
                #pragma unroll
                for (int u = 0; u < 20; ++u) tmp += leftS[u] * MS[n * 400 + u * 20 + tid];
            }
            WAVEBAR();
            if (tid < 20) leftS[tid] = tmp;
            WAVEBAR();
        }
        if (tid < 10) {
            float s = 0.f;
            #pragma unroll
            for (int u = 0; u < 20; ++u) s += leftS[u] * lvS[u * 10 + tid];
            out[b * 10 + tid] = s;
        }
    }
}

// ---------------------------------------------------------------------------
extern "C" void kernel_launch(void* const* d_in, const int* in_sizes, int n_in,
                              void* d_out, int out_size, void* d_ws, size_t ws_size,
                              hipStream_t stream)
{
    const float* x      = (const float*)d_in[0];
    const float* cores1 = (const float*)d_in[1];
    const float* label1 = (const float*)d_in[2];
    const float* g1     = (const float*)d_in[3];
    const float* b1     = (const float*)d_in[4];
    const float* cores2 = (const float*)d_in[5];
    const float* label2 = (const float*)d_in[6];
    const float* g2     = (const float*)d_in[7];
    const float* b2     = (const float*)d_in[8];
    const float* cores3 = (const float*)d_in[9];
    const float* label3 = (const float*)d_in[10];
    const float* g3     = (const float*)d_in[11];
    const float* b3     = (const float*)d_in[12];
    const float* coresF = (const float*)d_in[13];
    const float* labelF = (const float*)d_in[14];

    float* ws  = (float*)d_ws;
    float* z1  = ws + Z1_OFF;
    float* z2  = ws + Z2_OFF;
    float* z3  = ws + Z3_OFF;
    float* gs1 = ws + GS1_OFF; float* gq1 = ws + GQ1_OFF;
    float* gs2 = ws + GS2_OFF; float* gq2 = ws + GQ2_OFF;
    float* gs3 = ws + GS3_OFF; float* gq3 = ws + GQ3_OFF;
    float* lv2 = ws + LV2_OFF;
    float* lv3 = ws + LV3_OFF;
    _Float16* Wh2 = (_Float16*)(ws + WH2_OFF);
    _Float16* Wh3 = (_Float16*)(ws + WH3_OFF);

    fused1_kernel<<<256, 512, 0, stream>>>(x, cores1, label1,
                                           cores2, cores3, label2, label3,
                                           z1, gs1, gq1,
                                           Wh2, Wh3, lv2, lv3, gs2);
    stageN_kernel<2><<<dim3(64, 2), 256, 0, stream>>>(z1, Wh2, lv2, gs1, gq1, g1, b1,
                                                      z2, gs2, gq2);
    stageN_kernel<3><<<dim3(16, 2), 256, 0, stream>>>(z2, Wh3, lv3, gs2, gq2, g2, b2,
                                                      z3, gs3, gq3);
    final_kernel<<<128, 256, 0, stream>>>(z3, coresF, labelF, g3, b3,
                                          gs3, gq3, (float*)d_out);
}